// Round 12
// baseline (2692.622 us; speedup 1.0000x reference)
//
#include <hip/hip_runtime.h>
#include <cstdint>
#include <cstddef>
#include <cstring>

#define H 8192
#define NNZ 1000000
#define B 128
#define T 64

typedef unsigned int u32;
typedef u32 u32x2 __attribute__((ext_vector_type(2)));

__device__ inline float bf_lo(u32 w) { return __uint_as_float(w << 16); }
__device__ inline float bf_hi(u32 w) { return __uint_as_float(w & 0xffff0000u); }
__device__ inline unsigned short f2bf(float f) {        // RNE float->bf16
    u32 v = __float_as_uint(f);
    v += 0x7fffu + ((v >> 16) & 1u);
    return (unsigned short)(v >> 16);
}
__device__ inline u32 pack_bf16(float a, float b) {
    return (u32)f2bf(a) | ((u32)f2bf(b) << 16);
}
__device__ inline float fast_tanh(float x) {
    float e = __expf(2.0f * x);
    return 1.0f - 2.0f / (e + 1.0f);
}

// ---------------- the proven gather-accumulate row body (R5..R10) ----------------
// bf16 operand, 2 columns per gather instruction (lane halves), 32-bit voffset vs
// wave-uniform base, 16-deep MLP. basep points at a [*][64] u32 (bf16-pair) matrix.
__device__ inline void spmm_row(const int* __restrict__ rp, const int2* __restrict__ pair,
                                const char* __restrict__ basep, int r, bool hi, u32 i8,
                                float& ax, float& ay, float& az, float& aw) {
    int s = rp[r], e = rp[r + 1];
    int j = s;
    for (; j + 16 <= e; j += 16) {
        int2 q[16];
        #pragma unroll
        for (int u = 0; u < 16; ++u) q[u] = pair[j + u];
        u32x2 g[8];
        #pragma unroll
        for (int u = 0; u < 8; ++u) {
            u32 c = (u32)(hi ? q[2 * u + 1].x : q[2 * u].x);
            g[u] = *(const u32x2*)(basep + ((c << 8) + i8));
        }
        #pragma unroll
        for (int u = 0; u < 8; ++u) {
            float v = __int_as_float(hi ? q[2 * u + 1].y : q[2 * u].y);
            ax = fmaf(v, bf_lo(g[u].x), ax);
            ay = fmaf(v, bf_hi(g[u].x), ay);
            az = fmaf(v, bf_lo(g[u].y), az);
            aw = fmaf(v, bf_hi(g[u].y), aw);
        }
    }
    for (; j + 2 <= e; j += 2) {
        int2 q0 = pair[j], q1 = pair[j + 1];
        u32 c = (u32)(hi ? q1.x : q0.x);
        u32x2 g = *(const u32x2*)(basep + ((c << 8) + i8));
        float v = __int_as_float(hi ? q1.y : q0.y);
        ax = fmaf(v, bf_lo(g.x), ax);
        ay = fmaf(v, bf_hi(g.x), ay);
        az = fmaf(v, bf_lo(g.y), az);
        aw = fmaf(v, bf_hi(g.y), aw);
    }
    if (j < e) {
        int2 q0 = pair[j];
        u32 c = (u32)q0.x;
        u32x2 g = *(const u32x2*)(basep + ((c << 8) + i8));
        float v = hi ? 0.0f : __int_as_float(q0.y);
        ax = fmaf(v, bf_lo(g.x), ax);
        ay = fmaf(v, bf_hi(g.x), ay);
        az = fmaf(v, bf_lo(g.y), az);
        aw = fmaf(v, bf_hi(g.y), aw);
    }
}

// ---------------- CSR build (ih+hh merged per launch, proven R11) ----------------
__global__ void hist2_kernel(const int* __restrict__ rows_a, const int* __restrict__ rows_b,
                             int* __restrict__ cnt_a, int* __restrict__ cnt_b) {
    int j = blockIdx.x * blockDim.x + threadIdx.x;
    if (j < NNZ) atomicAdd(&cnt_a[rows_a[j]], 1);
    else if (j < 2 * NNZ) atomicAdd(&cnt_b[rows_b[j - NNZ]], 1);
}

__global__ void scan_kernel(const int* __restrict__ cnt0, int* __restrict__ rp0, int* __restrict__ cur0,
                            const int* __restrict__ cnt1, int* __restrict__ rp1, int* __restrict__ cur1) {
    const int* cnt = (blockIdx.x == 0) ? cnt0 : cnt1;
    int* rp  = (blockIdx.x == 0) ? rp0 : rp1;
    int* cur = (blockIdx.x == 0) ? cur0 : cur1;
    __shared__ int buf[1024];
    __shared__ int carry;
    int tid = threadIdx.x;
    if (tid == 0) carry = 0;
    __syncthreads();
    for (int base = 0; base < H; base += 1024) {
        int v = cnt[base + tid];
        buf[tid] = v;
        __syncthreads();
        for (int off = 1; off < 1024; off <<= 1) {
            int t = (tid >= off) ? buf[tid - off] : 0;
            __syncthreads();
            buf[tid] += t;
            __syncthreads();
        }
        int incl = buf[tid];
        int excl = incl - v;
        int c = carry;
        rp[base + tid]  = c + excl;
        cur[base + tid] = c + excl;
        __syncthreads();
        if (tid == 1023) carry = c + incl;
        __syncthreads();
    }
    if (tid == 0) rp[H] = carry;
}

__global__ void scatter2_kernel(const int* __restrict__ ra, const int* __restrict__ ca,
                                const float* __restrict__ va, int* __restrict__ cur_a,
                                int2* __restrict__ pa,
                                const int* __restrict__ rb, const int* __restrict__ cb,
                                const float* __restrict__ vb, int* __restrict__ cur_b,
                                int2* __restrict__ pb) {
    int j = blockIdx.x * blockDim.x + threadIdx.x;
    if (j < NNZ) {
        int r = ra[j];
        int p = atomicAdd(&cur_a[r], 1);
        pa[p] = make_int2(ca[j], __float_as_int(va[j]));
    } else if (j < 2 * NNZ) {
        int jj = j - NNZ;
        int r = rb[jj];
        int p = atomicAdd(&cur_b[r], 1);
        pb[p] = make_int2(cb[jj], __float_as_int(vb[jj]));
    }
}

// ---------------- counting sort of hh rows by length -> order[] ----------------
// 1 block, 1024 threads. Lengths clamped to 1023 (mean 122, max ~190).
// Balanced pairing: wave w processes order[w] (long end) + order[8191-w] (short end).
__global__ void __launch_bounds__(1024) sort_rows_kernel(const int* __restrict__ cnt,
                                                         int* __restrict__ order) {
    __shared__ int hist[1024];
    __shared__ int cursor[1024];
    int tid = threadIdx.x;
    hist[tid] = 0;
    __syncthreads();
    for (int r = tid; r < H; r += 1024) {
        int len = cnt[r]; if (len > 1023) len = 1023;
        atomicAdd(&hist[len], 1);
    }
    __syncthreads();
    int v = hist[tid];
    cursor[tid] = v;
    __syncthreads();
    for (int off = 1; off < 1024; off <<= 1) {
        int t = (tid >= off) ? cursor[tid - off] : 0;
        __syncthreads();
        cursor[tid] += t;
        __syncthreads();
    }
    int excl = cursor[tid] - v;
    __syncthreads();
    cursor[tid] = excl;
    __syncthreads();
    for (int r = tid; r < H; r += 1024) {
        int len = cnt[r]; if (len > 1023) len = 1023;
        int p = atomicAdd(&cursor[len], 1);
        order[H - 1 - p] = r;   // descending length: order[0] = longest
    }
}

// ---------------- transpose + bf16-pack: x [B][T*H] fp32 -> xTb [T*H][64] u32 (bf16 pairs) ----------------
__global__ void transpose_bf16_kernel(const float* __restrict__ src, u32* __restrict__ dst) {
    __shared__ float tile[32][33];
    int c0 = blockIdx.x * 32;    // T*H dim
    int r0 = blockIdx.y * 32;    // B dim
    int x = threadIdx.x, y = threadIdx.y;
    #pragma unroll
    for (int i = y; i < 32; i += 8) {
        tile[i][x] = src[(size_t)(r0 + i) * (T * H) + (c0 + x)];
    }
    __syncthreads();
    int tid = y * 32 + x;        // 256 threads, 512 words to write
    #pragma unroll
    for (int idx = tid; idx < 32 * 16; idx += 256) {
        int row = idx >> 4, w = idx & 15;
        u32 word = pack_bf16(tile[2 * w][row], tile[2 * w + 1][row]);
        dst[(size_t)(c0 + row) * 64 + (r0 >> 1) + w] = word;
    }
}

// ---------------- final transpose: outb [T*H][64] u32 (bf16 pairs) -> d_out [B][T*H] f32 ----------------
__global__ void transpose_out_kernel(const u32* __restrict__ src, float* __restrict__ dst) {
    __shared__ u32 tile[32][33];
    int c0 = blockIdx.x * 32;    // flat T*H index base
    int w0 = blockIdx.y * 32;    // u32-word (batch-pair) index base
    int x = threadIdx.x, y = threadIdx.y;
    #pragma unroll
    for (int i = y; i < 32; i += 8) {
        tile[i][x] = src[(size_t)(c0 + i) * 64 + (w0 + x)];
    }
    __syncthreads();
    #pragma unroll
    for (int i = y; i < 64; i += 8) {
        int w = i >> 1;
        u32 word = tile[x][w];
        float val = (i & 1) ? bf_hi(word) : bf_lo(word);
        dst[(size_t)(2 * w0 + i) * (size_t)(T * H) + (c0 + x)] = val;
    }
}

// ---------------- ih precompute: pre[t,h,:] = bias + spmm(ih, x_t), bf16-packed output ----------------
// 1 wave/row, blockIdx-only row derivation (scalar CSR stream), XCD swizzle (XCD k owns
// t in [8k,8k+8) so its 2MB x-slice stays L2-resident).
// NOTE (R5/R8/R10 post-mortem): at the measured TCP line-service wall ~2.45 cyc/line/CU
// (256M lines => ~1000us floor; R10 measured 1027us). Load imbalance self-corrects here
// because 131072 blocks stream through the CUs. Don't touch.
__global__ void __launch_bounds__(64) ih_pre_kernel(
    const int* __restrict__ rp, const int2* __restrict__ pair,
    const u32* __restrict__ xTb, u32* __restrict__ pre,
    const float* __restrict__ bias_ih, const float* __restrict__ bias_hh) {
    int bid = blockIdx.x;
    int xcd = bid & 7;
    int i0  = bid >> 3;
    int t   = (xcd << 3) + (i0 >> 13);
    int r   = i0 & (H - 1);
    int lane = threadIdx.x;
    bool hi = lane >= 32;
    int i = lane & 31;
    const char* __restrict__ xtb = (const char*)(xTb + (size_t)t * H * 64);  // uniform base
    const u32 i8 = (u32)i * 8u;
    float ax = 0.f, ay = 0.f, az = 0.f, aw = 0.f;
    spmm_row(rp, pair, xtb, r, hi, i8, ax, ay, az, aw);
    float tx = ax + __shfl_xor(ax, 32, 64);
    float ty = ay + __shfl_xor(ay, 32, 64);
    float tz = az + __shfl_xor(az, 32, 64);
    float tw = aw + __shfl_xor(aw, 32, 64);
    if (lane < 32) {
        float bias = bias_ih[r] + bias_hh[r];
        u32x2 pw;
        pw.x = pack_bf16(tx + bias, ty + bias);
        pw.y = pack_bf16(tz + bias, tw + bias);
        __builtin_nontemporal_store(pw, (u32x2*)(pre + ((size_t)t * H + r) * 64) + i);
    }
}

// ---------------- one recurrence step, pair-balanced ----------------
// R11 post-mortem: all step blocks are co-resident (8 blocks/CU), so the kernel ends when
// the LONGEST row ends (max of 8192 Poisson(122) ~ 1.38x mean — the measured 21us vs
// 16.6us wall). Fix: wave w does order[w] (long) + order[8191-w] (short): pair sums
// concentrate at 2x mean. Grid 1024 blocks x 4 waves = 4096 waves covering all rows.
// hprev==nullptr => step 0 (h=0): tanh(pre) only.
__global__ void __launch_bounds__(256) step_kernel(
    const int* __restrict__ rp, const int2* __restrict__ pair,
    const int* __restrict__ order,
    const u32* __restrict__ hprev, u32* __restrict__ hout,
    const u32* __restrict__ pre_t) {
    const int tid  = threadIdx.x;
    const int wav  = tid >> 6;
    const int lane = tid & 63;
    const bool hi  = lane >= 32;
    const int i    = lane & 31;
    const u32 i8   = (u32)i * 8u;
    const int w = ((int)blockIdx.x << 2) + wav;        // 0..4095
    #pragma unroll
    for (int half = 0; half < 2; ++half) {
        const int r = __builtin_amdgcn_readfirstlane(order[half ? (H - 1 - w) : w]);
        u32x2 pw = __builtin_nontemporal_load((const u32x2*)pre_t + (size_t)r * 32 + i);
        float ax = 0.f, ay = 0.f, az = 0.f, aw = 0.f;
        if (hprev) {
            spmm_row(rp, pair, (const char*)hprev, r, hi, i8, ax, ay, az, aw);
            ax += __shfl_xor(ax, 32, 64);
            ay += __shfl_xor(ay, 32, 64);
            az += __shfl_xor(az, 32, 64);
            aw += __shfl_xor(aw, 32, 64);
        }
        if (lane < 32) {
            float h0 = fast_tanh(ax + bf_lo(pw.x));
            float h1 = fast_tanh(ay + bf_hi(pw.x));
            float h2v = fast_tanh(az + bf_lo(pw.y));
            float h3 = fast_tanh(aw + bf_hi(pw.y));
            u32x2 hw;
            hw.x = pack_bf16(h0, h1);
            hw.y = pack_bf16(h2v, h3);
            ((u32x2*)hout)[(size_t)r * 32 + i] = hw;   // h for next step == outT row (bf16)
        }
    }
}

extern "C" void kernel_launch(void* const* d_in, const int* in_sizes, int n_in,
                              void* d_out, int out_size, void* d_ws, size_t ws_size,
                              hipStream_t stream) {
    const float* x        = (const float*)d_in[0];
    const int*   ih_idx   = (const int*)d_in[1];
    const float* ih_val   = (const float*)d_in[2];
    const int*   hh_idx   = (const int*)d_in[3];
    const float* hh_val   = (const float*)d_in[4];
    const float* bias_ih  = (const float*)d_in[5];
    const float* bias_hh  = (const float*)d_in[6];
    const int* ih_rows = ih_idx;
    const int* ih_cols = ih_idx + NNZ;
    const int* hh_rows = hh_idx;
    const int* hh_cols = hh_idx + NNZ;

    char* ws = (char*)d_ws;
    size_t off = 0;
    auto alloc = [&](size_t bytes) -> void* {
        void* p = ws + off;
        off += (bytes + 255) & ~(size_t)255;
        return p;
    };
    u32*   xTb     = (u32*)  alloc((size_t)T * H * 64 * 4);  // 128 MB bf16-packed x^T
    u32*   pre     = (u32*)  alloc((size_t)T * H * 64 * 4);  // 128 MB bf16-packed pre-activations
    u32*   outb    = (u32*)  alloc((size_t)T * H * 64 * 4);  // 128 MB bf16-packed h/outT
    int2*  pair_ih = (int2*) alloc((size_t)NNZ * 8);
    int2*  pair_hh = (int2*) alloc((size_t)NNZ * 8);
    int*   rp_ih   = (int*)  alloc((size_t)(H + 1) * 4);
    int*   rp_hh   = (int*)  alloc((size_t)(H + 1) * 4);
    int*   cnt_ih  = (int*)  alloc((size_t)H * 4);
    int*   cnt_hh  = (int*)  alloc((size_t)H * 4);
    int*   cur_ih  = (int*)  alloc((size_t)H * 4);
    int*   cur_hh  = (int*)  alloc((size_t)H * 4);
    int*   order   = (int*)  alloc((size_t)H * 4);

    hipMemsetAsync(cnt_ih, 0, (size_t)H * 4, stream);
    hipMemsetAsync(cnt_hh, 0, (size_t)H * 4, stream);

    const int tb = 256;
    const int gb2 = (2 * NNZ + tb - 1) / tb;
    hist2_kernel<<<gb2, tb, 0, stream>>>(ih_rows, hh_rows, cnt_ih, cnt_hh);
    scan_kernel<<<2, 1024, 0, stream>>>(cnt_ih, rp_ih, cur_ih, cnt_hh, rp_hh, cur_hh);
    scatter2_kernel<<<gb2, tb, 0, stream>>>(ih_rows, ih_cols, ih_val, cur_ih, pair_ih,
                                            hh_rows, hh_cols, hh_val, cur_hh, pair_hh);
    sort_rows_kernel<<<1, 1024, 0, stream>>>(cnt_hh, order);

    // x [B][T*H] fp32 -> xTb [T*H][64] bf16-pairs
    dim3 tblk(32, 8);
    dim3 tgrid1((T * H) / 32, B / 32);
    transpose_bf16_kernel<<<tgrid1, tblk, 0, stream>>>(x, xTb);

    // all-timestep ih spmm + bias
    ih_pre_kernel<<<T * H, 64, 0, stream>>>(rp_ih, pair_ih, xTb, pre, bias_ih, bias_hh);

    // sequential recurrence: step 0 is tanh(pre) only; step t gathers from outb[t-1]
    step_kernel<<<H / 8, 256, 0, stream>>>(rp_hh, pair_hh, order, (const u32*)nullptr,
                                           outb, pre);
    for (int t = 1; t < T; ++t) {
        step_kernel<<<H / 8, 256, 0, stream>>>(rp_hh, pair_hh, order,
                                               outb + (size_t)(t - 1) * H * 64,
                                               outb + (size_t)t * H * 64,
                                               pre + (size_t)t * H * 64);
    }

    // outb [T*H][64] bf16 -> d_out [B][T*H] f32
    dim3 tgrid2((T * H) / 32, 2);
    transpose_out_kernel<<<tgrid2, tblk, 0, stream>>>(outb, (float*)d_out);
}

// Round 13
// 2558.517 us; speedup vs baseline: 1.0524x; 1.0524x over previous
//
#include <hip/hip_runtime.h>
#include <cstdint>
#include <cstddef>
#include <cstring>

#define H 8192
#define NNZ 1000000
#define B 128
#define T 64

typedef unsigned int u32;
typedef u32 u32x2 __attribute__((ext_vector_type(2)));

__device__ inline float bf_lo(u32 w) { return __uint_as_float(w << 16); }
__device__ inline float bf_hi(u32 w) { return __uint_as_float(w & 0xffff0000u); }
__device__ inline unsigned short f2bf(float f) {        // RNE float->bf16
    u32 v = __float_as_uint(f);
    v += 0x7fffu + ((v >> 16) & 1u);
    return (unsigned short)(v >> 16);
}
__device__ inline u32 pack_bf16(float a, float b) {
    return (u32)f2bf(a) | ((u32)f2bf(b) << 16);
}
__device__ inline float fast_tanh(float x) {
    float e = __expf(2.0f * x);
    return 1.0f - 2.0f / (e + 1.0f);
}

// ---------------- the proven gather-accumulate row body (R5..R10) ----------------
// bf16 operand, 2 columns per gather instruction (lane halves), 32-bit voffset vs
// wave-uniform base, 16-deep MLP. basep points at a [*][64] u32 (bf16-pair) matrix.
__device__ inline void spmm_row(const int* __restrict__ rp, const int2* __restrict__ pair,
                                const char* __restrict__ basep, int r, bool hi, u32 i8,
                                float& ax, float& ay, float& az, float& aw) {
    int s = rp[r], e = rp[r + 1];
    int j = s;
    for (; j + 16 <= e; j += 16) {
        int2 q[16];
        #pragma unroll
        for (int u = 0; u < 16; ++u) q[u] = pair[j + u];
        u32x2 g[8];
        #pragma unroll
        for (int u = 0; u < 8; ++u) {
            u32 c = (u32)(hi ? q[2 * u + 1].x : q[2 * u].x);
            g[u] = *(const u32x2*)(basep + ((c << 8) + i8));
        }
        #pragma unroll
        for (int u = 0; u < 8; ++u) {
            float v = __int_as_float(hi ? q[2 * u + 1].y : q[2 * u].y);
            ax = fmaf(v, bf_lo(g[u].x), ax);
            ay = fmaf(v, bf_hi(g[u].x), ay);
            az = fmaf(v, bf_lo(g[u].y), az);
            aw = fmaf(v, bf_hi(g[u].y), aw);
        }
    }
    for (; j + 2 <= e; j += 2) {
        int2 q0 = pair[j], q1 = pair[j + 1];
        u32 c = (u32)(hi ? q1.x : q0.x);
        u32x2 g = *(const u32x2*)(basep + ((c << 8) + i8));
        float v = __int_as_float(hi ? q1.y : q0.y);
        ax = fmaf(v, bf_lo(g.x), ax);
        ay = fmaf(v, bf_hi(g.x), ay);
        az = fmaf(v, bf_lo(g.y), az);
        aw = fmaf(v, bf_hi(g.y), aw);
    }
    if (j < e) {
        int2 q0 = pair[j];
        u32 c = (u32)q0.x;
        u32x2 g = *(const u32x2*)(basep + ((c << 8) + i8));
        float v = hi ? 0.0f : __int_as_float(q0.y);
        ax = fmaf(v, bf_lo(g.x), ax);
        ay = fmaf(v, bf_hi(g.x), ay);
        az = fmaf(v, bf_lo(g.y), az);
        aw = fmaf(v, bf_hi(g.y), aw);
    }
}

// ---------------- CSR build (ih+hh merged per launch, proven R11/R12) ----------------
__global__ void hist2_kernel(const int* __restrict__ rows_a, const int* __restrict__ rows_b,
                             int* __restrict__ cnt_a, int* __restrict__ cnt_b) {
    int j = blockIdx.x * blockDim.x + threadIdx.x;
    if (j < NNZ) atomicAdd(&cnt_a[rows_a[j]], 1);
    else if (j < 2 * NNZ) atomicAdd(&cnt_b[rows_b[j - NNZ]], 1);
}

__global__ void scan_kernel(const int* __restrict__ cnt0, int* __restrict__ rp0, int* __restrict__ cur0,
                            const int* __restrict__ cnt1, int* __restrict__ rp1, int* __restrict__ cur1) {
    const int* cnt = (blockIdx.x == 0) ? cnt0 : cnt1;
    int* rp  = (blockIdx.x == 0) ? rp0 : rp1;
    int* cur = (blockIdx.x == 0) ? cur0 : cur1;
    __shared__ int buf[1024];
    __shared__ int carry;
    int tid = threadIdx.x;
    if (tid == 0) carry = 0;
    __syncthreads();
    for (int base = 0; base < H; base += 1024) {
        int v = cnt[base + tid];
        buf[tid] = v;
        __syncthreads();
        for (int off = 1; off < 1024; off <<= 1) {
            int t = (tid >= off) ? buf[tid - off] : 0;
            __syncthreads();
            buf[tid] += t;
            __syncthreads();
        }
        int incl = buf[tid];
        int excl = incl - v;
        int c = carry;
        rp[base + tid]  = c + excl;
        cur[base + tid] = c + excl;
        __syncthreads();
        if (tid == 1023) carry = c + incl;
        __syncthreads();
    }
    if (tid == 0) rp[H] = carry;
}

__global__ void scatter2_kernel(const int* __restrict__ ra, const int* __restrict__ ca,
                                const float* __restrict__ va, int* __restrict__ cur_a,
                                int2* __restrict__ pa,
                                const int* __restrict__ rb, const int* __restrict__ cb,
                                const float* __restrict__ vb, int* __restrict__ cur_b,
                                int2* __restrict__ pb) {
    int j = blockIdx.x * blockDim.x + threadIdx.x;
    if (j < NNZ) {
        int r = ra[j];
        int p = atomicAdd(&cur_a[r], 1);
        pa[p] = make_int2(ca[j], __float_as_int(va[j]));
    } else if (j < 2 * NNZ) {
        int jj = j - NNZ;
        int r = rb[jj];
        int p = atomicAdd(&cur_b[r], 1);
        pb[p] = make_int2(cb[jj], __float_as_int(vb[jj]));
    }
}

// ---------------- transpose + bf16-pack: x [B][T*H] fp32 -> xTb [T*H][64] u32 (bf16 pairs) ----------------
__global__ void transpose_bf16_kernel(const float* __restrict__ src, u32* __restrict__ dst) {
    __shared__ float tile[32][33];
    int c0 = blockIdx.x * 32;    // T*H dim
    int r0 = blockIdx.y * 32;    // B dim
    int x = threadIdx.x, y = threadIdx.y;
    #pragma unroll
    for (int i = y; i < 32; i += 8) {
        tile[i][x] = src[(size_t)(r0 + i) * (T * H) + (c0 + x)];
    }
    __syncthreads();
    int tid = y * 32 + x;        // 256 threads, 512 words to write
    #pragma unroll
    for (int idx = tid; idx < 32 * 16; idx += 256) {
        int row = idx >> 4, w = idx & 15;
        u32 word = pack_bf16(tile[2 * w][row], tile[2 * w + 1][row]);
        dst[(size_t)(c0 + row) * 64 + (r0 >> 1) + w] = word;
    }
}

// ---------------- final transpose: outb [T*H][64] u32 (bf16 pairs) -> d_out [B][T*H] f32 ----------------
__global__ void transpose_out_kernel(const u32* __restrict__ src, float* __restrict__ dst) {
    __shared__ u32 tile[32][33];
    int c0 = blockIdx.x * 32;    // flat T*H index base
    int w0 = blockIdx.y * 32;    // u32-word (batch-pair) index base
    int x = threadIdx.x, y = threadIdx.y;
    #pragma unroll
    for (int i = y; i < 32; i += 8) {
        tile[i][x] = src[(size_t)(c0 + i) * 64 + (w0 + x)];
    }
    __syncthreads();
    #pragma unroll
    for (int i = y; i < 64; i += 8) {
        int w = i >> 1;
        u32 word = tile[x][w];
        float val = (i & 1) ? bf_hi(word) : bf_lo(word);
        dst[(size_t)(2 * w0 + i) * (size_t)(T * H) + (c0 + x)] = val;
    }
}

// ---------------- ih precompute: pre[t,h,:] = bias + spmm(ih, x_t), bf16-packed output ----------------
// 1 wave/row, blockIdx-only row derivation (scalar CSR stream), XCD swizzle (XCD k owns
// t in [8k,8k+8) so its 2MB x-slice stays L2-resident).
// ROOFLINE NOTE: 256M lines x 2.45 cyc/line/CU / (256CU x 2.4GHz) = 1021us floor;
// measured 1028us (+0.7%). The 2.45 cyc/line constant validated across fp32 (R4 2.30),
// bf16 (R5/R8/R10 2.41-2.46), and stream copy (m13, 2.62). Don't touch.
__global__ void __launch_bounds__(64) ih_pre_kernel(
    const int* __restrict__ rp, const int2* __restrict__ pair,
    const u32* __restrict__ xTb, u32* __restrict__ pre,
    const float* __restrict__ bias_ih, const float* __restrict__ bias_hh) {
    int bid = blockIdx.x;
    int xcd = bid & 7;
    int i0  = bid >> 3;
    int t   = (xcd << 3) + (i0 >> 13);
    int r   = i0 & (H - 1);
    int lane = threadIdx.x;
    bool hi = lane >= 32;
    int i = lane & 31;
    const char* __restrict__ xtb = (const char*)(xTb + (size_t)t * H * 64);  // uniform base
    const u32 i8 = (u32)i * 8u;
    float ax = 0.f, ay = 0.f, az = 0.f, aw = 0.f;
    spmm_row(rp, pair, xtb, r, hi, i8, ax, ay, az, aw);
    float tx = ax + __shfl_xor(ax, 32, 64);
    float ty = ay + __shfl_xor(ay, 32, 64);
    float tz = az + __shfl_xor(az, 32, 64);
    float tw = aw + __shfl_xor(aw, 32, 64);
    if (lane < 32) {
        float bias = bias_ih[r] + bias_hh[r];
        u32x2 pw;
        pw.x = pack_bf16(tx + bias, ty + bias);
        pw.y = pack_bf16(tz + bias, tw + bias);
        __builtin_nontemporal_store(pw, (u32x2*)(pre + ((size_t)t * H + r) * 64) + i);
    }
}

// ---------------- one recurrence step (R10 optimum) ----------------
// 4 waves/block, one row per wave (readfirstlane keeps CSR stream scalar), grid 2048
// blocks = all co-resident at 32 waves/CU (full MLP). Kernel time = line floor 16.0us
// x max-row tail (~1.38, Poisson max-of-8192) ~= 21us; balancing attempts that halve
// occupancy (R12) or extend the kernel (R11) both regressed — leave as is.
// hprev==nullptr => step 0 (h=0): tanh(pre) only.
__global__ void __launch_bounds__(256) step_kernel(
    const int* __restrict__ rp, const int2* __restrict__ pair,
    const u32* __restrict__ hprev, u32* __restrict__ hout,
    const u32* __restrict__ pre_t) {
    const int tid  = threadIdx.x;
    const int wav  = tid >> 6;
    const int lane = tid & 63;
    const bool hi  = lane >= 32;
    const int i    = lane & 31;
    const u32 i8   = (u32)i * 8u;
    const int r = __builtin_amdgcn_readfirstlane(((int)blockIdx.x << 2) + wav);
    // hoisted pre load: overlaps with gather latency
    u32x2 pw = __builtin_nontemporal_load((const u32x2*)pre_t + (size_t)r * 32 + i);
    float ax = 0.f, ay = 0.f, az = 0.f, aw = 0.f;
    if (hprev) {
        spmm_row(rp, pair, (const char*)hprev, r, hi, i8, ax, ay, az, aw);
        ax += __shfl_xor(ax, 32, 64);
        ay += __shfl_xor(ay, 32, 64);
        az += __shfl_xor(az, 32, 64);
        aw += __shfl_xor(aw, 32, 64);
    }
    if (lane < 32) {
        float h0 = fast_tanh(ax + bf_lo(pw.x));
        float h1 = fast_tanh(ay + bf_hi(pw.x));
        float h2v = fast_tanh(az + bf_lo(pw.y));
        float h3 = fast_tanh(aw + bf_hi(pw.y));
        u32x2 hw;
        hw.x = pack_bf16(h0, h1);
        hw.y = pack_bf16(h2v, h3);
        ((u32x2*)hout)[(size_t)r * 32 + i] = hw;   // h for next step == outT row (bf16)
    }
}

extern "C" void kernel_launch(void* const* d_in, const int* in_sizes, int n_in,
                              void* d_out, int out_size, void* d_ws, size_t ws_size,
                              hipStream_t stream) {
    const float* x        = (const float*)d_in[0];
    const int*   ih_idx   = (const int*)d_in[1];
    const float* ih_val   = (const float*)d_in[2];
    const int*   hh_idx   = (const int*)d_in[3];
    const float* hh_val   = (const float*)d_in[4];
    const float* bias_ih  = (const float*)d_in[5];
    const float* bias_hh  = (const float*)d_in[6];
    const int* ih_rows = ih_idx;
    const int* ih_cols = ih_idx + NNZ;
    const int* hh_rows = hh_idx;
    const int* hh_cols = hh_idx + NNZ;

    char* ws = (char*)d_ws;
    size_t off = 0;
    auto alloc = [&](size_t bytes) -> void* {
        void* p = ws + off;
        off += (bytes + 255) & ~(size_t)255;
        return p;
    };
    u32*   xTb     = (u32*)  alloc((size_t)T * H * 64 * 4);  // 128 MB bf16-packed x^T
    u32*   pre     = (u32*)  alloc((size_t)T * H * 64 * 4);  // 128 MB bf16-packed pre-activations
    u32*   outb    = (u32*)  alloc((size_t)T * H * 64 * 4);  // 128 MB bf16-packed h/outT
    int2*  pair_ih = (int2*) alloc((size_t)NNZ * 8);
    int2*  pair_hh = (int2*) alloc((size_t)NNZ * 8);
    int*   rp_ih   = (int*)  alloc((size_t)(H + 1) * 4);
    int*   rp_hh   = (int*)  alloc((size_t)(H + 1) * 4);
    int*   cnt_ih  = (int*)  alloc((size_t)H * 4);
    int*   cnt_hh  = (int*)  alloc((size_t)H * 4);
    int*   cur_ih  = (int*)  alloc((size_t)H * 4);
    int*   cur_hh  = (int*)  alloc((size_t)H * 4);

    hipMemsetAsync(cnt_ih, 0, (size_t)H * 4, stream);
    hipMemsetAsync(cnt_hh, 0, (size_t)H * 4, stream);

    const int tb = 256;
    const int gb2 = (2 * NNZ + tb - 1) / tb;
    hist2_kernel<<<gb2, tb, 0, stream>>>(ih_rows, hh_rows, cnt_ih, cnt_hh);
    scan_kernel<<<2, 1024, 0, stream>>>(cnt_ih, rp_ih, cur_ih, cnt_hh, rp_hh, cur_hh);
    scatter2_kernel<<<gb2, tb, 0, stream>>>(ih_rows, ih_cols, ih_val, cur_ih, pair_ih,
                                            hh_rows, hh_cols, hh_val, cur_hh, pair_hh);

    // x [B][T*H] fp32 -> xTb [T*H][64] bf16-pairs
    dim3 tblk(32, 8);
    dim3 tgrid1((T * H) / 32, B / 32);
    transpose_bf16_kernel<<<tgrid1, tblk, 0, stream>>>(x, xTb);

    // all-timestep ih spmm + bias
    ih_pre_kernel<<<T * H, 64, 0, stream>>>(rp_ih, pair_ih, xTb, pre, bias_ih, bias_hh);

    // sequential recurrence: step 0 is tanh(pre) only; step t gathers from outb[t-1]
    step_kernel<<<H / 4, 256, 0, stream>>>(rp_hh, pair_hh, (const u32*)nullptr,
                                           outb, pre);
    for (int t = 1; t < T; ++t) {
        step_kernel<<<H / 4, 256, 0, stream>>>(rp_hh, pair_hh,
                                               outb + (size_t)(t - 1) * H * 64,
                                               outb + (size_t)t * H * 64,
                                               pre + (size_t)t * H * 64);
    }

    // outb [T*H][64] bf16 -> d_out [B][T*H] f32
    dim3 tgrid2((T * H) / 32, 2);
    transpose_out_kernel<<<tgrid2, tblk, 0, stream>>>(outb, (float*)d_out);
}